// Round 8
// baseline (164.098 us; speedup 1.0000x reference)
//
#include <hip/hip_runtime.h>
#include <hip/hip_bf16.h>
#include <cstdint>

#define L_SEQ 1024
#define HID_DIM 512
#define N_HEADS 8
#define HEAD_DIM 64
#define BATCH 8

typedef __attribute__((ext_vector_type(8))) short bf16x8;
typedef __attribute__((ext_vector_type(4))) float f32x4;

__device__ __forceinline__ ushort f2bf(float v) {
  __hip_bfloat16 hb = __float2bfloat16(v);
  return *(ushort*)&hb;
}

// Convert f32 -> bf16: x (4,194,304) then Wq,Wk,Wv,Wo (262,144 each).
__global__ __launch_bounds__(256)
void prep_convert(const float* __restrict__ x, const float* __restrict__ Wq,
                  const float* __restrict__ Wk, const float* __restrict__ Wv,
                  const float* __restrict__ Wo, ushort* __restrict__ dst) {
  const size_t gid = (size_t)blockIdx.x * 256 + threadIdx.x;
  const size_t e = gid * 8;
  const float* src;
  size_t loc;
  if (e < 4194304) {
    src = x; loc = e;
  } else {
    const size_t r = e - 4194304;
    const int wsel = (int)(r >> 18);
    loc = r & 262143;
    src = (wsel == 0) ? Wq : (wsel == 1) ? Wk : (wsel == 2) ? Wv : Wo;
  }
  float4 v0 = *(const float4*)(src + loc);
  float4 v1 = *(const float4*)(src + loc + 4);
  ushort u[8];
  u[0] = f2bf(v0.x); u[1] = f2bf(v0.y); u[2] = f2bf(v0.z); u[3] = f2bf(v0.w);
  u[4] = f2bf(v1.x); u[5] = f2bf(v1.y); u[6] = f2bf(v1.z); u[7] = f2bf(v1.w);
  *(uint4*)(dst + e) = *(uint4*)u;
}

// lens[b] = number of un-padded rows in batch b (layout-detecting; see round 3)
__global__ __launch_bounds__(256)
void lens_kernel(const uint8_t* __restrict__ pm, int* __restrict__ lens) {
  __shared__ int flag;
  __shared__ int part[256];
  const int b = blockIdx.x, tid = threadIdx.x;
  if (tid == 0) flag = 0;
  __syncthreads();
  const unsigned* pw = (const unsigned*)pm;
  unsigned any = 0;
  for (int i = tid; i < 2048; i += 256) any |= (pw[i] > 1u);
  if (any) flag = 1;
  __syncthreads();
  int c = 0;
  if (flag) {
    unsigned v = pw[b * 256 + tid];
    c = (int)((v & 0xFFu) == 0) + (int)(((v >> 8) & 0xFFu) == 0) +
        (int)(((v >> 16) & 0xFFu) == 0) + (int)(((v >> 24) & 0xFFu) == 0);
  } else {
    const int* pi = (const int*)pm;
    c = (int)(pi[b * 1024 + tid * 4 + 0] == 0) + (int)(pi[b * 1024 + tid * 4 + 1] == 0) +
        (int)(pi[b * 1024 + tid * 4 + 2] == 0) + (int)(pi[b * 1024 + tid * 4 + 3] == 0);
  }
  part[tid] = c;
  __syncthreads();
  for (int s = 128; s > 0; s >>= 1) {
    if (tid < s) part[tid] += part[tid + s];
    __syncthreads();
  }
  if (tid == 0) lens[b] = part[0];
}

#define LOAD_FRAGS4(av, bv, ks)                                             \
  {                                                                         \
    _Pragma("unroll") for (int t = 0; t < 4; ++t) {                         \
      av[t] = *(const bf16x8*)(Abase + (size_t)t * 16 * 512 + (ks) * 32);   \
      bv[t] = *(const bf16x8*)(Bbase + (size_t)t * 16 * 512 + (ks) * 32);   \
    }                                                                       \
  }
#define DO_MFMA44(av, bv)                                                   \
  {                                                                         \
    _Pragma("unroll") for (int i = 0; i < 4; ++i)                           \
        _Pragma("unroll") for (int j = 0; j < 4; ++j) acc[i][j] =           \
            __builtin_amdgcn_mfma_f32_16x16x32_bf16(av[i], bv[j],           \
                                                    acc[i][j], 0, 0, 0);    \
  }

// Fused QKV GEMM, 64x64 tile per 1-wave block. grid (128, 8, 3).
__global__ __launch_bounds__(64)
void qkv_gemm(const ushort* __restrict__ xb, const ushort* __restrict__ wqb,
              const ushort* __restrict__ wkb, const ushort* __restrict__ wvb,
              const float* __restrict__ bq, const float* __restrict__ bk,
              const float* __restrict__ bv, ushort* __restrict__ qb,
              ushort* __restrict__ kb, ushort* __restrict__ vT) {
  const int z = blockIdx.z;
  const int lane = threadIdx.x;
  const int l15 = lane & 15, g = lane >> 4;
  const ushort* A = (z == 2) ? wvb : xb;
  const ushort* B = (z == 0) ? wqb : (z == 1) ? wkb : xb;
  const float* bias = (z == 0) ? bq : (z == 1) ? bk : bv;
  const int M0 = ((z == 2) ? blockIdx.y : blockIdx.x) * 64;
  const int N0 = ((z == 2) ? blockIdx.x : blockIdx.y) * 64;

  const ushort* Abase = A + (size_t)(M0 + l15) * 512 + 8 * g;
  const ushort* Bbase = B + (size_t)(N0 + l15) * 512 + 8 * g;

  f32x4 acc[4][4];
#pragma unroll
  for (int i = 0; i < 4; ++i)
#pragma unroll
    for (int j = 0; j < 4; ++j) acc[i][j] = (f32x4){0.f, 0.f, 0.f, 0.f};

  bf16x8 aA[4], bA[4], aB[4], bB[4];
  LOAD_FRAGS4(aA, bA, 0);
  LOAD_FRAGS4(aB, bB, 1);
#pragma unroll
  for (int ks = 0; ks < 16; ks += 2) {
    DO_MFMA44(aA, bA);
    if (ks + 2 < 16) LOAD_FRAGS4(aA, bA, ks + 2);
    DO_MFMA44(aB, bB);
    if (ks + 3 < 16) LOAD_FRAGS4(aB, bB, ks + 3);
  }

  if (z < 2) {
    ushort* out = (z == 0) ? qb : kb;
    float bn[4];
#pragma unroll
    for (int nt = 0; nt < 4; ++nt) bn[nt] = bias[N0 + nt * 16 + l15];
#pragma unroll
    for (int mt = 0; mt < 4; ++mt)
#pragma unroll
      for (int nt = 0; nt < 4; ++nt)
#pragma unroll
        for (int r = 0; r < 4; ++r) {
          const int m = M0 + mt * 16 + 4 * g + r;
          const int n = N0 + nt * 16 + l15;
          out[(size_t)m * 512 + n] = f2bf(acc[mt][nt][r] + bn[nt]);
        }
  } else {
#pragma unroll
    for (int mt = 0; mt < 4; ++mt)
#pragma unroll
      for (int r = 0; r < 4; ++r) {
        const int m = M0 + mt * 16 + 4 * g + r;  // hid index of V
        const float bm = bias[m];
#pragma unroll
        for (int nt = 0; nt < 4; ++nt) {
          const int tok = N0 + nt * 16 + l15;
          const size_t off = ((size_t)((tok >> 10) * 512 + m)) * 1024 + (tok & 1023);
          vT[off] = f2bf(acc[mt][nt][r] + bm);
        }
      }
  }
}

// Final projection: out = ab*Wo^T + bo, f32 out. 32x64 tile. grid (256, 8).
__global__ __launch_bounds__(64)
void out_gemm(const ushort* __restrict__ A, const ushort* __restrict__ B,
              const float* __restrict__ bias, float* __restrict__ out) {
  const int lane = threadIdx.x;
  const int l15 = lane & 15, g = lane >> 4;
  const int M0 = blockIdx.x * 32, N0 = blockIdx.y * 64;
  const ushort* Abase = A + (size_t)(M0 + l15) * 512 + 8 * g;
  const ushort* Bbase = B + (size_t)(N0 + l15) * 512 + 8 * g;

  f32x4 acc[2][4];
#pragma unroll
  for (int i = 0; i < 2; ++i)
#pragma unroll
    for (int j = 0; j < 4; ++j) acc[i][j] = (f32x4){0.f, 0.f, 0.f, 0.f};

  bf16x8 aA[2], bA[4], aB[2], bB[4];
#define LOAD_FRAGS2(av, bv, ks)                                             \
  {                                                                         \
    _Pragma("unroll") for (int t = 0; t < 2; ++t)                           \
      av[t] = *(const bf16x8*)(Abase + (size_t)t * 16 * 512 + (ks) * 32);   \
    _Pragma("unroll") for (int t = 0; t < 4; ++t)                           \
      bv[t] = *(const bf16x8*)(Bbase + (size_t)t * 16 * 512 + (ks) * 32);   \
  }
#define DO_MFMA24(av, bv)                                                   \
  {                                                                         \
    _Pragma("unroll") for (int i = 0; i < 2; ++i)                           \
        _Pragma("unroll") for (int j = 0; j < 4; ++j) acc[i][j] =           \
            __builtin_amdgcn_mfma_f32_16x16x32_bf16(av[i], bv[j],           \
                                                    acc[i][j], 0, 0, 0);    \
  }
  LOAD_FRAGS2(aA, bA, 0);
  LOAD_FRAGS2(aB, bB, 1);
#pragma unroll
  for (int ks = 0; ks < 16; ks += 2) {
    DO_MFMA24(aA, bA);
    if (ks + 2 < 16) LOAD_FRAGS2(aA, bA, ks + 2);
    DO_MFMA24(aB, bB);
    if (ks + 3 < 16) LOAD_FRAGS2(aB, bB, ks + 3);
  }
#undef LOAD_FRAGS2
#undef DO_MFMA24

  float bn[4];
#pragma unroll
  for (int nt = 0; nt < 4; ++nt) bn[nt] = bias[N0 + nt * 16 + l15];
#pragma unroll
  for (int mt = 0; mt < 2; ++mt)
#pragma unroll
    for (int nt = 0; nt < 4; ++nt)
#pragma unroll
      for (int r = 0; r < 4; ++r) {
        const int m = M0 + mt * 16 + 4 * g + r;
        const int n = N0 + nt * 16 + l15;
        out[(size_t)m * 512 + n] = acc[mt][nt][r] + bn[nt];
      }
}

// MFMA flash attention. grid (x=8 batches, y=64 q-tiles, z=2 head-groups).
// Linear block id % 8 = batch -> XCD locality (round-7 verified: FETCH 19MB).
// 256-thread blocks (4 waves = 4 heads): finer packing quantum -> more
// resident waves/CU (round-7 was stuck at ~5 waves/CU with 512-thr blocks).
// LPT: t = 63 - y (big tiles first). tb double-buffered across chunks.
__global__ __launch_bounds__(256)
void attn_mfma(const ushort* __restrict__ qb, const ushort* __restrict__ kb,
               const ushort* __restrict__ vT, const int* __restrict__ tbm,
               const float* __restrict__ temb, const int* __restrict__ lens,
               ushort* __restrict__ ab) {
  __shared__ char pbuf[4][2048];
  const int tid = threadIdx.x;
  const int w = tid >> 6;
  const int lane = tid & 63;
  const int l15 = lane & 15, g = lane >> 4;
  const int b = blockIdx.x;          // batch -> XCD (locality)
  const int t = 63 - blockIdx.y;     // LPT: longest tiles first
  const int h = blockIdx.z * 4 + w;  // head
  const int len = lens[b];
  const int qbase = t * 16;

  const float te_src = temb[(lane & 7) * N_HEADS + h] * 1.44269504f;

  bf16x8 qf[2];
  {
    const ushort* qrow = qb + (size_t)(b * L_SEQ + qbase + l15) * HID_DIM + h * HEAD_DIM + 8 * g;
    qf[0] = *(const bf16x8*)(qrow);
    qf[1] = *(const bf16x8*)(qrow + 32);
  }

  f32x4 O[4];
#pragma unroll
  for (int ct = 0; ct < 4; ++ct) O[ct] = (f32x4){0.f, 0.f, 0.f, 0.f};
  float ssum[4] = {0.f, 0.f, 0.f, 0.f};

  const int ke = (qbase + 16 < len) ? (qbase + 16) : len;
  const int nch = (qbase < len) ? ((ke + 63) >> 6) : 0;
  const int* tbq = tbm + (size_t)(b * L_SEQ + qbase) * L_SEQ;

#define LOAD_TB(dst, cc)                                                    \
  {                                                                         \
    const int* tb_p = tbq + (cc) * 64;                                      \
    _Pragma("unroll") for (int kt = 0; kt < 4; ++kt)                        \
        _Pragma("unroll") for (int r = 0; r < 4; ++r)                       \
            dst[kt][r] = tb_p[(4 * g + r) * L_SEQ + 16 * kt + l15];         \
  }

#define COMPUTE_CHUNK(tbv, c)                                               \
  {                                                                         \
    const int kc = (c) * 64;                                                \
    bf16x8 kf[4][2];                                                        \
    _Pragma("unroll") for (int kt = 0; kt < 4; ++kt) {                      \
      const ushort* krow = kb + (size_t)(b * L_SEQ + kc + 16 * kt + l15) * HID_DIM + h * HEAD_DIM + 8 * g; \
      kf[kt][0] = *(const bf16x8*)(krow);                                   \
      kf[kt][1] = *(const bf16x8*)(krow + 32);                              \
    }                                                                       \
    bf16x8 vf[2][4];                                                        \
    _Pragma("unroll") for (int kblk = 0; kblk < 2; ++kblk)                  \
        _Pragma("unroll") for (int ct = 0; ct < 4; ++ct) {                  \
      const ushort* vrow = vT + (size_t)((b * 8 + h) * 64 + 16 * ct + l15) * L_SEQ + kc + 32 * kblk + 8 * g; \
      vf[kblk][ct] = *(const bf16x8*)(vrow);                                \
    }                                                                       \
    f32x4 s[4];                                                             \
    __builtin_amdgcn_s_setprio(1);                                          \
    _Pragma("unroll") for (int kt = 0; kt < 4; ++kt) {                      \
      s[kt] = (f32x4){0.f, 0.f, 0.f, 0.f};                                  \
      s[kt] = __builtin_amdgcn_mfma_f32_16x16x32_bf16(qf[0], kf[kt][0], s[kt], 0, 0, 0); \
      s[kt] = __builtin_amdgcn_mfma_f32_16x16x32_bf16(qf[1], kf[kt][1], s[kt], 0, 0, 0); \
    }                                                                       \
    __builtin_amdgcn_s_setprio(0);                                          \
    _Pragma("unroll") for (int kt = 0; kt < 4; ++kt) {                      \
      const int kg = kc + 16 * kt + l15;                                    \
      _Pragma("unroll") for (int r = 0; r < 4; ++r) {                       \
        const int lr = 4 * g + r;                                           \
        const int qg = qbase + lr;                                          \
        const float te2 = __int_as_float(                                   \
            __builtin_amdgcn_ds_bpermute(tbv[kt][r] << 2, __float_as_int(te_src))); \
        float p = exp2f(fmaf(s[kt][r], 0.18033688f, te2));                  \
        p = (kg <= qg && qg < len) ? p : 0.0f;                              \
        const ushort pbits = f2bf(p);                                       \
        ssum[r] += __bfloat162float(*(const __hip_bfloat16*)&pbits);        \
        const int off = ((lr * 128 + (16 * kt + l15) * 2) ^ ((lr & 7) << 4)); \
        *(ushort*)&pbuf[w][off] = pbits;                                    \
      }                                                                     \
    }                                                                       \
    _Pragma("unroll") for (int kblk = 0; kblk < 2; ++kblk) {                \
      const int off = ((l15 * 128 + kblk * 64 + 16 * g) ^ ((l15 & 7) << 4)); \
      const bf16x8 pf = *(const bf16x8*)(&pbuf[w][off]);                    \
      __builtin_amdgcn_s_setprio(1);                                        \
      _Pragma("unroll") for (int ct = 0; ct < 4; ++ct)                      \
        O[ct] = __builtin_amdgcn_mfma_f32_16x16x32_bf16(pf, vf[kblk][ct], O[ct], 0, 0, 0); \
      __builtin_amdgcn_s_setprio(0);                                        \
    }                                                                       \
  }

  int tbA[4][4], tbB[4][4];
  if (nch > 0) LOAD_TB(tbA, 0);
  int c = 0;
  while (c < nch) {
    if (c + 1 < nch) LOAD_TB(tbB, c + 1);
    COMPUTE_CHUNK(tbA, c);
    ++c;
    if (c >= nch) break;
    if (c + 1 < nch) LOAD_TB(tbA, c + 1);
    COMPUTE_CHUNK(tbB, c);
    ++c;
  }
#undef LOAD_TB
#undef COMPUTE_CHUNK

#pragma unroll
  for (int m = 1; m <= 8; m <<= 1) {
#pragma unroll
    for (int r = 0; r < 4; ++r) ssum[r] += __shfl_xor(ssum[r], m, 64);
  }
  float inv[4];
#pragma unroll
  for (int r = 0; r < 4; ++r) {
    const int qg = qbase + 4 * g + r;
    inv[r] = (qg < len) ? 1.0f / ssum[r] : 0.0f;
  }
#pragma unroll
  for (int ct = 0; ct < 4; ++ct)
#pragma unroll
    for (int r = 0; r < 4; ++r) {
      const int qg = qbase + 4 * g + r;
      ab[(size_t)(b * L_SEQ + qg) * HID_DIM + h * HEAD_DIM + 16 * ct + l15] =
          f2bf(O[ct][r] * inv[r]);
    }
}

extern "C" void kernel_launch(void* const* d_in, const int* in_sizes, int n_in,
                              void* d_out, int out_size, void* d_ws, size_t ws_size,
                              hipStream_t stream) {
  const float* x    = (const float*)d_in[0];
  const int*   tbm  = (const int*)d_in[1];
  // d_in[2] = causal_mask: deterministic triu(k=1) -> handled analytically
  const uint8_t* pm = (const uint8_t*)d_in[3];
  const float* Wq = (const float*)d_in[4];
  const float* bq = (const float*)d_in[5];
  const float* Wk = (const float*)d_in[6];
  const float* bk = (const float*)d_in[7];
  const float* Wv = (const float*)d_in[8];
  const float* bv = (const float*)d_in[9];
  const float* Wo = (const float*)d_in[10];
  const float* bo = (const float*)d_in[11];
  const float* temb = (const float*)d_in[12];
  float* out = (float*)d_out;

  const size_t NTOK = (size_t)BATCH * L_SEQ * HID_DIM;  // 4,194,304
  const size_t NW = 262144;
  ushort* ab  = (ushort*)d_ws;        // bf16 attention output [8192][512]
  ushort* xb  = ab + NTOK;            // bf16 x
  ushort* wqb = xb + NTOK;
  ushort* wkb = wqb + NW;
  ushort* wvb = wkb + NW;
  ushort* wob = wvb + NW;
  ushort* qb  = wob + NW;             // bf16 Q [tok][512]
  ushort* kb  = qb + NTOK;            // bf16 K [tok][512]
  ushort* vT  = kb + NTOK;            // bf16 V^T [b*8+h][64][1024]
  int* lens   = (int*)(vT + NTOK);

  prep_convert<<<2560, 256, 0, stream>>>(x, Wq, Wk, Wv, Wo, xb);
  lens_kernel<<<8, 256, 0, stream>>>(pm, lens);
  qkv_gemm<<<dim3(128, 8, 3), 64, 0, stream>>>(xb, wqb, wkb, wvb, bq, bk, bv, qb, kb, vT);
  attn_mfma<<<dim3(8, 64, 2), 256, 0, stream>>>(qb, kb, vT, tbm, temb, lens, ab);
  out_gemm<<<dim3(256, 8), 64, 0, stream>>>(ab, wob, bo, out);
}

// Round 9
// 128.860 us; speedup vs baseline: 1.2735x; 1.2735x over previous
//
#include <hip/hip_runtime.h>
#include <hip/hip_bf16.h>
#include <cstdint>

#define L_SEQ 1024
#define HID_DIM 512
#define N_HEADS 8
#define HEAD_DIM 64
#define BATCH 8

typedef __attribute__((ext_vector_type(8))) short bf16x8;
typedef __attribute__((ext_vector_type(4))) float f32x4;

__device__ __forceinline__ ushort f2bf(float v) {
  __hip_bfloat16 hb = __float2bfloat16(v);
  return *(ushort*)&hb;
}

// Convert f32 -> bf16: x (4,194,304) then Wq,Wk,Wv,Wo (262,144 each).
__global__ __launch_bounds__(256)
void prep_convert(const float* __restrict__ x, const float* __restrict__ Wq,
                  const float* __restrict__ Wk, const float* __restrict__ Wv,
                  const float* __restrict__ Wo, ushort* __restrict__ dst) {
  const size_t gid = (size_t)blockIdx.x * 256 + threadIdx.x;
  const size_t e = gid * 8;
  const float* src;
  size_t loc;
  if (e < 4194304) {
    src = x; loc = e;
  } else {
    const size_t r = e - 4194304;
    const int wsel = (int)(r >> 18);
    loc = r & 262143;
    src = (wsel == 0) ? Wq : (wsel == 1) ? Wk : (wsel == 2) ? Wv : Wo;
  }
  float4 v0 = *(const float4*)(src + loc);
  float4 v1 = *(const float4*)(src + loc + 4);
  ushort u[8];
  u[0] = f2bf(v0.x); u[1] = f2bf(v0.y); u[2] = f2bf(v0.z); u[3] = f2bf(v0.w);
  u[4] = f2bf(v1.x); u[5] = f2bf(v1.y); u[6] = f2bf(v1.z); u[7] = f2bf(v1.w);
  *(uint4*)(dst + e) = *(uint4*)u;
}

// lens[b] = number of un-padded rows in batch b (layout-detecting; see round 3)
__global__ __launch_bounds__(256)
void lens_kernel(const uint8_t* __restrict__ pm, int* __restrict__ lens) {
  __shared__ int flag;
  __shared__ int part[256];
  const int b = blockIdx.x, tid = threadIdx.x;
  if (tid == 0) flag = 0;
  __syncthreads();
  const unsigned* pw = (const unsigned*)pm;
  unsigned any = 0;
  for (int i = tid; i < 2048; i += 256) any |= (pw[i] > 1u);
  if (any) flag = 1;
  __syncthreads();
  int c = 0;
  if (flag) {
    unsigned v = pw[b * 256 + tid];
    c = (int)((v & 0xFFu) == 0) + (int)(((v >> 8) & 0xFFu) == 0) +
        (int)(((v >> 16) & 0xFFu) == 0) + (int)(((v >> 24) & 0xFFu) == 0);
  } else {
    const int* pi = (const int*)pm;
    c = (int)(pi[b * 1024 + tid * 4 + 0] == 0) + (int)(pi[b * 1024 + tid * 4 + 1] == 0) +
        (int)(pi[b * 1024 + tid * 4 + 2] == 0) + (int)(pi[b * 1024 + tid * 4 + 3] == 0);
  }
  part[tid] = c;
  __syncthreads();
  for (int s = 128; s > 0; s >>= 1) {
    if (tid < s) part[tid] += part[tid + s];
    __syncthreads();
  }
  if (tid == 0) lens[b] = part[0];
}

#define LOAD_FRAGS4(av, bv, ks)                                             \
  {                                                                         \
    _Pragma("unroll") for (int t = 0; t < 4; ++t) {                         \
      av[t] = *(const bf16x8*)(Abase + (size_t)t * 16 * 512 + (ks) * 32);   \
      bv[t] = *(const bf16x8*)(Bbase + (size_t)t * 16 * 512 + (ks) * 32);   \
    }                                                                       \
  }
#define DO_MFMA44(av, bv)                                                   \
  {                                                                         \
    _Pragma("unroll") for (int i = 0; i < 4; ++i)                           \
        _Pragma("unroll") for (int j = 0; j < 4; ++j) acc[i][j] =           \
            __builtin_amdgcn_mfma_f32_16x16x32_bf16(av[i], bv[j],           \
                                                    acc[i][j], 0, 0, 0);    \
  }

// Fused QKV GEMM, 64x64 tile per 1-wave block. grid (128, 8, 3).
__global__ __launch_bounds__(64)
void qkv_gemm(const ushort* __restrict__ xb, const ushort* __restrict__ wqb,
              const ushort* __restrict__ wkb, const ushort* __restrict__ wvb,
              const float* __restrict__ bq, const float* __restrict__ bk,
              const float* __restrict__ bv, ushort* __restrict__ qb,
              ushort* __restrict__ kb, ushort* __restrict__ vT) {
  const int z = blockIdx.z;
  const int lane = threadIdx.x;
  const int l15 = lane & 15, g = lane >> 4;
  const ushort* A = (z == 2) ? wvb : xb;
  const ushort* B = (z == 0) ? wqb : (z == 1) ? wkb : xb;
  const float* bias = (z == 0) ? bq : (z == 1) ? bk : bv;
  const int M0 = ((z == 2) ? blockIdx.y : blockIdx.x) * 64;
  const int N0 = ((z == 2) ? blockIdx.x : blockIdx.y) * 64;

  const ushort* Abase = A + (size_t)(M0 + l15) * 512 + 8 * g;
  const ushort* Bbase = B + (size_t)(N0 + l15) * 512 + 8 * g;

  f32x4 acc[4][4];
#pragma unroll
  for (int i = 0; i < 4; ++i)
#pragma unroll
    for (int j = 0; j < 4; ++j) acc[i][j] = (f32x4){0.f, 0.f, 0.f, 0.f};

  bf16x8 aA[4], bA[4], aB[4], bB[4];
  LOAD_FRAGS4(aA, bA, 0);
  LOAD_FRAGS4(aB, bB, 1);
#pragma unroll
  for (int ks = 0; ks < 16; ks += 2) {
    DO_MFMA44(aA, bA);
    if (ks + 2 < 16) LOAD_FRAGS4(aA, bA, ks + 2);
    DO_MFMA44(aB, bB);
    if (ks + 3 < 16) LOAD_FRAGS4(aB, bB, ks + 3);
  }

  if (z < 2) {
    ushort* out = (z == 0) ? qb : kb;
    float bn[4];
#pragma unroll
    for (int nt = 0; nt < 4; ++nt) bn[nt] = bias[N0 + nt * 16 + l15];
#pragma unroll
    for (int mt = 0; mt < 4; ++mt)
#pragma unroll
      for (int nt = 0; nt < 4; ++nt)
#pragma unroll
        for (int r = 0; r < 4; ++r) {
          const int m = M0 + mt * 16 + 4 * g + r;
          const int n = N0 + nt * 16 + l15;
          out[(size_t)m * 512 + n] = f2bf(acc[mt][nt][r] + bn[nt]);
        }
  } else {
#pragma unroll
    for (int mt = 0; mt < 4; ++mt)
#pragma unroll
      for (int r = 0; r < 4; ++r) {
        const int m = M0 + mt * 16 + 4 * g + r;  // hid index of V
        const float bm = bias[m];
#pragma unroll
        for (int nt = 0; nt < 4; ++nt) {
          const int tok = N0 + nt * 16 + l15;
          const size_t off = ((size_t)((tok >> 10) * 512 + m)) * 1024 + (tok & 1023);
          vT[off] = f2bf(acc[mt][nt][r] + bm);
        }
      }
  }
}

// Final projection: out = ab*Wo^T + bo, f32 out. 32x64 tile. grid (256, 8).
__global__ __launch_bounds__(64)
void out_gemm(const ushort* __restrict__ A, const ushort* __restrict__ B,
              const float* __restrict__ bias, float* __restrict__ out) {
  const int lane = threadIdx.x;
  const int l15 = lane & 15, g = lane >> 4;
  const int M0 = blockIdx.x * 32, N0 = blockIdx.y * 64;
  const ushort* Abase = A + (size_t)(M0 + l15) * 512 + 8 * g;
  const ushort* Bbase = B + (size_t)(N0 + l15) * 512 + 8 * g;

  f32x4 acc[2][4];
#pragma unroll
  for (int i = 0; i < 2; ++i)
#pragma unroll
    for (int j = 0; j < 4; ++j) acc[i][j] = (f32x4){0.f, 0.f, 0.f, 0.f};

  bf16x8 aA[2], bA[4], aB[2], bB[4];
#define LOAD_FRAGS2(av, bv, ks)                                             \
  {                                                                         \
    _Pragma("unroll") for (int t = 0; t < 2; ++t)                           \
      av[t] = *(const bf16x8*)(Abase + (size_t)t * 16 * 512 + (ks) * 32);   \
    _Pragma("unroll") for (int t = 0; t < 4; ++t)                           \
      bv[t] = *(const bf16x8*)(Bbase + (size_t)t * 16 * 512 + (ks) * 32);   \
  }
#define DO_MFMA24(av, bv)                                                   \
  {                                                                         \
    _Pragma("unroll") for (int i = 0; i < 2; ++i)                           \
        _Pragma("unroll") for (int j = 0; j < 4; ++j) acc[i][j] =           \
            __builtin_amdgcn_mfma_f32_16x16x32_bf16(av[i], bv[j],           \
                                                    acc[i][j], 0, 0, 0);    \
  }
  LOAD_FRAGS2(aA, bA, 0);
  LOAD_FRAGS2(aB, bB, 1);
#pragma unroll
  for (int ks = 0; ks < 16; ks += 2) {
    DO_MFMA24(aA, bA);
    if (ks + 2 < 16) LOAD_FRAGS2(aA, bA, ks + 2);
    DO_MFMA24(aB, bB);
    if (ks + 3 < 16) LOAD_FRAGS2(aB, bB, ks + 3);
  }
#undef LOAD_FRAGS2
#undef DO_MFMA24

  float bn[4];
#pragma unroll
  for (int nt = 0; nt < 4; ++nt) bn[nt] = bias[N0 + nt * 16 + l15];
#pragma unroll
  for (int mt = 0; mt < 2; ++mt)
#pragma unroll
    for (int nt = 0; nt < 4; ++nt)
#pragma unroll
      for (int r = 0; r < 4; ++r) {
        const int m = M0 + mt * 16 + 4 * g + r;
        const int n = N0 + nt * 16 + l15;
        out[(size_t)m * 512 + n] = acc[mt][nt][r] + bn[nt];
      }
}

// Cooperative flash attention. Block = (b, h, pair p): 4 waves share
// LDS-staged K/V chunks (double-buffered, XOR-swizzled both sides).
// Each wave owns 16 rows of q-group A=p AND 16 rows of q-group B=15-p:
// uniform 17 compute-chunks/block; kf/vf register fragments shared by
// both tiles. Grid (8,8,8): id%8 = b -> XCD locality.
__global__ __launch_bounds__(256, 2)
void attn_mfma(const ushort* __restrict__ qb, const ushort* __restrict__ kb,
               const ushort* __restrict__ vT, const int* __restrict__ tbm,
               const float* __restrict__ temb, const int* __restrict__ lens,
               ushort* __restrict__ ab) {
  __shared__ char kv[2][16384];   // [buf][K 8KB | V 8KB], swizzled
  __shared__ char pbuf[4][2048];  // per-wave P tile
  const int tid = threadIdx.x;
  const int w = tid >> 6;
  const int lane = tid & 63;
  const int l15 = lane & 15, g = lane >> 4;
  const int b = blockIdx.x, h = blockIdx.y, p = blockIdx.z;
  const int len = lens[b];
  const int GB = 15 - p;
  const int qbaseA = p * 64 + 16 * w;
  const int qbaseB = GB * 64 + 16 * w;

  const float te_src = temb[(lane & 7) * N_HEADS + h] * 1.44269504f;

  // ---- staging geometry: thread stages 2x16B of K and 2x16B of V ----
  const int r0 = tid >> 3, c0 = tid & 7;                 // f0 = tid
  const size_t kgrow = (size_t)(b * L_SEQ) * HID_DIM + h * HEAD_DIM + c0 * 8;
  const size_t vgrow = (size_t)((b * 8 + h) * 64 + r0) * L_SEQ + c0 * 8;
  const int so0 = (tid * 16) ^ ((r0 & 7) << 4);
  const int so1 = so0 + 4096;                            // f1 = tid+256 (row+32)
  uint4 skA, skB, svA, svB;

#define STAGE_LOAD(kc_)                                                      \
  skA = *(const uint4*)(kb + kgrow + (size_t)((kc_) + r0) * HID_DIM);        \
  skB = *(const uint4*)(kb + kgrow + (size_t)((kc_) + r0 + 32) * HID_DIM);   \
  svA = *(const uint4*)(vT + vgrow + (kc_));                                 \
  svB = *(const uint4*)(vT + vgrow + 32 * L_SEQ + (kc_));

#define STAGE_WRITE(dst)                                                     \
  *(uint4*)&(dst)[so0] = skA;                                                \
  *(uint4*)&(dst)[so1] = skB;                                                \
  *(uint4*)&(dst)[8192 + so0] = svA;                                         \
  *(uint4*)&(dst)[8192 + so1] = svB;

  // ---- Q fragments for both tiles ----
  bf16x8 qfA[2], qfB[2];
  {
    const ushort* qr = qb + (size_t)(b * L_SEQ + qbaseA + l15) * HID_DIM + h * HEAD_DIM + 8 * g;
    qfA[0] = *(const bf16x8*)(qr);
    qfA[1] = *(const bf16x8*)(qr + 32);
    qr = qb + (size_t)(b * L_SEQ + qbaseB + l15) * HID_DIM + h * HEAD_DIM + 8 * g;
    qfB[0] = *(const bf16x8*)(qr);
    qfB[1] = *(const bf16x8*)(qr + 32);
  }

  f32x4 OA[4], OB[4];
#pragma unroll
  for (int ct = 0; ct < 4; ++ct) {
    OA[ct] = (f32x4){0.f, 0.f, 0.f, 0.f};
    OB[ct] = (f32x4){0.f, 0.f, 0.f, 0.f};
  }
  float ssA[4] = {0.f, 0.f, 0.f, 0.f}, ssB[4] = {0.f, 0.f, 0.f, 0.f};
  bf16x8 kf[4][2], vf[2][4];
  int tbA_[4][4], tbB_[4][4];

  const int lenc = (len - 1) >> 6;
  const int nchB = (GB * 64 < len) ? ((GB < lenc ? GB : lenc) + 1) : 0;
  const int NCH = (p + 1 > nchB) ? (p + 1) : nchB;

#define LOAD_TB(dst, qbaseT, kc_)                                            \
  {                                                                          \
    const int* tb_p = tbm + (size_t)(b * L_SEQ + (qbaseT)) * L_SEQ + (kc_);  \
    _Pragma("unroll") for (int kt = 0; kt < 4; ++kt)                         \
      _Pragma("unroll") for (int r = 0; r < 4; ++r)                          \
        dst[kt][r] = tb_p[(4 * g + r) * L_SEQ + 16 * kt + l15];              \
  }

#define LOAD_KV_FRAGS(kvb)                                                   \
  _Pragma("unroll") for (int kt = 0; kt < 4; ++kt)                           \
    _Pragma("unroll") for (int db = 0; db < 2; ++db) {                       \
      const int off = ((2048 * kt + 128 * l15 + 16 * (g + 4 * db)) ^ ((l15 & 7) << 4)); \
      kf[kt][db] = *(const bf16x8*)&(kvb)[off];                              \
    }                                                                        \
  _Pragma("unroll") for (int kblk = 0; kblk < 2; ++kblk)                     \
    _Pragma("unroll") for (int ct = 0; ct < 4; ++ct) {                       \
      const int off = 8192 + ((2048 * ct + 128 * l15 + 16 * (4 * kblk + g)) ^ ((l15 & 7) << 4)); \
      vf[kblk][ct] = *(const bf16x8*)&(kvb)[off];                            \
    }

#define COMPUTE_TILE(qfv, Ov, ssumv, tbv, qbaseT, kc_)                       \
  {                                                                          \
    f32x4 s[4];                                                              \
    __builtin_amdgcn_s_setprio(1);                                           \
    _Pragma("unroll") for (int kt = 0; kt < 4; ++kt) {                       \
      s[kt] = (f32x4){0.f, 0.f, 0.f, 0.f};                                   \
      s[kt] = __builtin_amdgcn_mfma_f32_16x16x32_bf16(qfv[0], kf[kt][0], s[kt], 0, 0, 0); \
      s[kt] = __builtin_amdgcn_mfma_f32_16x16x32_bf16(qfv[1], kf[kt][1], s[kt], 0, 0, 0); \
    }                                                                        \
    __builtin_amdgcn_s_setprio(0);                                           \
    _Pragma("unroll") for (int kt = 0; kt < 4; ++kt) {                       \
      const int kg = (kc_) + 16 * kt + l15;                                  \
      _Pragma("unroll") for (int r = 0; r < 4; ++r) {                        \
        const int lr = 4 * g + r;                                            \
        const int qg = (qbaseT) + lr;                                        \
        const float te2 = __int_as_float(                                    \
            __builtin_amdgcn_ds_bpermute(tbv[kt][r] << 2, __float_as_int(te_src))); \
        float pp = exp2f(fmaf(s[kt][r], 0.18033688f, te2));                  \
        pp = (kg <= qg && qg < len) ? pp : 0.0f;                             \
        const ushort pbits = f2bf(pp);                                       \
        ssumv[r] += __bfloat162float(*(const __hip_bfloat16*)&pbits);        \
        const int off = ((lr * 128 + (16 * kt + l15) * 2) ^ ((lr & 7) << 4)); \
        *(ushort*)&pbuf[w][off] = pbits;                                     \
      }                                                                      \
    }                                                                        \
    _Pragma("unroll") for (int kblk = 0; kblk < 2; ++kblk) {                 \
      const int off = ((l15 * 128 + kblk * 64 + 16 * g) ^ ((l15 & 7) << 4)); \
      const bf16x8 pf = *(const bf16x8*)(&pbuf[w][off]);                     \
      __builtin_amdgcn_s_setprio(1);                                         \
      _Pragma("unroll") for (int ct = 0; ct < 4; ++ct)                       \
        Ov[ct] = __builtin_amdgcn_mfma_f32_16x16x32_bf16(pf, vf[kblk][ct], Ov[ct], 0, 0, 0); \
      __builtin_amdgcn_s_setprio(0);                                         \
    }                                                                        \
  }

  // ---- prologue: stage chunk 0 ----
  STAGE_LOAD(0);
  STAGE_WRITE(kv[0]);
  __syncthreads();

  int cur = 0;
  for (int c = 0; c < NCH; ++c) {
    const int kc = c * 64;
    const bool doB = (c < nchB);
    const bool doA = (c <= p);
    if (doB) LOAD_TB(tbB_, qbaseB, kc);
    if (doA) LOAD_TB(tbA_, qbaseA, kc);
    if (c + 1 < NCH) { STAGE_LOAD(kc + 64); }
    LOAD_KV_FRAGS(kv[cur]);
    if (doB) COMPUTE_TILE(qfB, OB, ssB, tbB_, qbaseB, kc);
    if (doA) COMPUTE_TILE(qfA, OA, ssA, tbA_, qbaseA, kc);
    if (c + 1 < NCH) { STAGE_WRITE(kv[cur ^ 1]); }
    __syncthreads();
    cur ^= 1;
  }

#define EPILOGUE(Ov, ssumv, qbaseT)                                          \
  {                                                                          \
    _Pragma("unroll") for (int m = 1; m <= 8; m <<= 1)                       \
      _Pragma("unroll") for (int r = 0; r < 4; ++r)                          \
        ssumv[r] += __shfl_xor(ssumv[r], m, 64);                             \
    _Pragma("unroll") for (int ct = 0; ct < 4; ++ct)                         \
      _Pragma("unroll") for (int r = 0; r < 4; ++r) {                        \
        const int qg = (qbaseT) + 4 * g + r;                                 \
        const float inv = (qg < len) ? 1.0f / ssumv[r] : 0.0f;               \
        ab[(size_t)(b * L_SEQ + qg) * HID_DIM + h * HEAD_DIM + 16 * ct + l15] = \
            f2bf(Ov[ct][r] * inv);                                           \
      }                                                                      \
  }

  EPILOGUE(OA, ssA, qbaseA);
  EPILOGUE(OB, ssB, qbaseB);
}

extern "C" void kernel_launch(void* const* d_in, const int* in_sizes, int n_in,
                              void* d_out, int out_size, void* d_ws, size_t ws_size,
                              hipStream_t stream) {
  const float* x    = (const float*)d_in[0];
  const int*   tbm  = (const int*)d_in[1];
  // d_in[2] = causal_mask: deterministic triu(k=1) -> handled analytically
  const uint8_t* pm = (const uint8_t*)d_in[3];
  const float* Wq = (const float*)d_in[4];
  const float* bq = (const float*)d_in[5];
  const float* Wk = (const float*)d_in[6];
  const float* bk = (const float*)d_in[7];
  const float* Wv = (const float*)d_in[8];
  const float* bv = (const float*)d_in[9];
  const float* Wo = (const float*)d_in[10];
  const float* bo = (const float*)d_in[11];
  const float* temb = (const float*)d_in[12];
  float* out = (float*)d_out;

  const size_t NTOK = (size_t)BATCH * L_SEQ * HID_DIM;  // 4,194,304
  const size_t NW = 262144;
  ushort* ab  = (ushort*)d_ws;        // bf16 attention output [8192][512]
  ushort* xb  = ab + NTOK;            // bf16 x
  ushort* wqb = xb + NTOK;
  ushort* wkb = wqb + NW;
  ushort* wvb = wkb + NW;
  ushort* wob = wvb + NW;
  ushort* qb  = wob + NW;             // bf16 Q [tok][512]
  ushort* kb  = qb + NTOK;            // bf16 K [tok][512]
  ushort* vT  = kb + NTOK;            // bf16 V^T [b*8+h][64][1024]
  int* lens   = (int*)(vT + NTOK);

  prep_convert<<<2560, 256, 0, stream>>>(x, Wq, Wk, Wv, Wo, xb);
  lens_kernel<<<8, 256, 0, stream>>>(pm, lens);
  qkv_gemm<<<dim3(128, 8, 3), 64, 0, stream>>>(xb, wqb, wkb, wvb, bq, bk, bv, qb, kb, vT);
  attn_mfma<<<dim3(8, 8, 8), 256, 0, stream>>>(qb, kb, vT, tbm, temb, lens, ab);
  out_gemm<<<dim3(256, 8), 64, 0, stream>>>(ab, wob, bo, out);
}

// Round 10
// 84.972 us; speedup vs baseline: 1.9312x; 1.5165x over previous
//
#include <hip/hip_runtime.h>
#include <hip/hip_bf16.h>
#include <cstdint>

#define L_SEQ 1024
#define HID_DIM 512
#define N_HEADS 8
#define HEAD_DIM 64
#define BATCH 8

typedef __attribute__((ext_vector_type(8))) short bf16x8;
typedef __attribute__((ext_vector_type(4))) float f32x4;

__device__ __forceinline__ ushort f2bf(float v) {
  __hip_bfloat16 hb = __float2bfloat16(v);
  return *(ushort*)&hb;
}

// Convert f32 -> bf16: x (4,194,304) then Wq,Wk,Wv,Wo (262,144 each).
__global__ __launch_bounds__(256)
void prep_convert(const float* __restrict__ x, const float* __restrict__ Wq,
                  const float* __restrict__ Wk, const float* __restrict__ Wv,
                  const float* __restrict__ Wo, ushort* __restrict__ dst) {
  const size_t gid = (size_t)blockIdx.x * 256 + threadIdx.x;
  const size_t e = gid * 8;
  const float* src;
  size_t loc;
  if (e < 4194304) {
    src = x; loc = e;
  } else {
    const size_t r = e - 4194304;
    const int wsel = (int)(r >> 18);
    loc = r & 262143;
    src = (wsel == 0) ? Wq : (wsel == 1) ? Wk : (wsel == 2) ? Wv : Wo;
  }
  float4 v0 = *(const float4*)(src + loc);
  float4 v1 = *(const float4*)(src + loc + 4);
  ushort u[8];
  u[0] = f2bf(v0.x); u[1] = f2bf(v0.y); u[2] = f2bf(v0.z); u[3] = f2bf(v0.w);
  u[4] = f2bf(v1.x); u[5] = f2bf(v1.y); u[6] = f2bf(v1.z); u[7] = f2bf(v1.w);
  *(uint4*)(dst + e) = *(uint4*)u;
}

// lens[b] = number of un-padded rows in batch b (layout-detecting; see round 3)
__global__ __launch_bounds__(256)
void lens_kernel(const uint8_t* __restrict__ pm, int* __restrict__ lens) {
  __shared__ int flag;
  __shared__ int part[256];
  const int b = blockIdx.x, tid = threadIdx.x;
  if (tid == 0) flag = 0;
  __syncthreads();
  const unsigned* pw = (const unsigned*)pm;
  unsigned any = 0;
  for (int i = tid; i < 2048; i += 256) any |= (pw[i] > 1u);
  if (any) flag = 1;
  __syncthreads();
  int c = 0;
  if (flag) {
    unsigned v = pw[b * 256 + tid];
    c = (int)((v & 0xFFu) == 0) + (int)(((v >> 8) & 0xFFu) == 0) +
        (int)(((v >> 16) & 0xFFu) == 0) + (int)(((v >> 24) & 0xFFu) == 0);
  } else {
    const int* pi = (const int*)pm;
    c = (int)(pi[b * 1024 + tid * 4 + 0] == 0) + (int)(pi[b * 1024 + tid * 4 + 1] == 0) +
        (int)(pi[b * 1024 + tid * 4 + 2] == 0) + (int)(pi[b * 1024 + tid * 4 + 3] == 0);
  }
  part[tid] = c;
  __syncthreads();
  for (int s = 128; s > 0; s >>= 1) {
    if (tid < s) part[tid] += part[tid + s];
    __syncthreads();
  }
  if (tid == 0) lens[b] = part[0];
}

// ---------------------------------------------------------------------------
// LDS-staged fused QKV GEMM (m97-style). Block = 256 thr = 4 waves, tile
// 128x128, BK=32, double-buffered LDS. Row stride 80 B (16 B pad) -> row
// starts cycle 8 bank phases -> conflict-free b128 reads/writes.
// grid (64, 4, 3): z=0 Q, z=1 K (bf16 row-major), z=2 V^T (roles swapped).
__global__ __launch_bounds__(256, 3)
void qkv_lds(const ushort* __restrict__ xb, const ushort* __restrict__ wqb,
             const ushort* __restrict__ wkb, const ushort* __restrict__ wvb,
             const float* __restrict__ bq, const float* __restrict__ bk,
             const float* __restrict__ bv, ushort* __restrict__ qb,
             ushort* __restrict__ kb, ushort* __restrict__ vT) {
  __shared__ char lds[2][20480];  // A[128 rows x 80B] | B at +10240
  const int tid = threadIdx.x;
  const int w = tid >> 6, lane = tid & 63;
  const int l15 = lane & 15, g = lane >> 4;
  const int z = blockIdx.z;
  const ushort* A = (z == 2) ? wvb : xb;
  const ushort* B = (z == 0) ? wqb : (z == 1) ? wkb : xb;
  const float* bias = (z == 0) ? bq : (z == 1) ? bk : bv;
  const int M0 = ((z == 2) ? blockIdx.y : blockIdx.x) * 128;
  const int N0 = ((z == 2) ? blockIdx.x : blockIdx.y) * 128;

  // staging: thread covers rows sr, sr+64 of A and B, 16B slice sc
  const int sr = tid >> 2, sc = tid & 3;
  const ushort* Ag = A + (size_t)(M0 + sr) * 512 + sc * 8;
  const ushort* Bg = B + (size_t)(N0 + sr) * 512 + sc * 8;
  const int wro = sr * 80 + sc * 16;
  uint4 sa0, sa1, sb0, sb1;

#define QSTAGE_LOAD(kc_)                                      \
  sa0 = *(const uint4*)(Ag + (kc_) * 32);                     \
  sa1 = *(const uint4*)(Ag + (size_t)64 * 512 + (kc_) * 32);  \
  sb0 = *(const uint4*)(Bg + (kc_) * 32);                     \
  sb1 = *(const uint4*)(Bg + (size_t)64 * 512 + (kc_) * 32);
#define QSTAGE_WRITE(buf)                                     \
  *(uint4*)&(buf)[wro] = sa0;                                 \
  *(uint4*)&(buf)[wro + 64 * 80] = sa1;                       \
  *(uint4*)&(buf)[10240 + wro] = sb0;                         \
  *(uint4*)&(buf)[10240 + wro + 64 * 80] = sb1;

  // wave quadrant: rows wm*64.., cols wn*64..
  const int wm = w >> 1, wn = w & 1;
  const int aro = (wm * 64 + l15) * 80 + g * 16;          // + t*1280
  const int bro = 10240 + (wn * 64 + l15) * 80 + g * 16;  // + t*1280

  f32x4 acc[4][4];
#pragma unroll
  for (int i = 0; i < 4; ++i)
#pragma unroll
    for (int j = 0; j < 4; ++j) acc[i][j] = (f32x4){0.f, 0.f, 0.f, 0.f};

  QSTAGE_LOAD(0);
  QSTAGE_WRITE(lds[0]);
  __syncthreads();
  int cur = 0;
#pragma unroll 1
  for (int kc = 0; kc < 16; ++kc) {
    if (kc + 1 < 16) { QSTAGE_LOAD(kc + 1); }
    bf16x8 av[4], bv[4];
#pragma unroll
    for (int t = 0; t < 4; ++t) {
      av[t] = *(const bf16x8*)&lds[cur][aro + t * 1280];
      bv[t] = *(const bf16x8*)&lds[cur][bro + t * 1280];
    }
    __builtin_amdgcn_s_setprio(1);
#pragma unroll
    for (int i = 0; i < 4; ++i)
#pragma unroll
      for (int j = 0; j < 4; ++j)
        acc[i][j] = __builtin_amdgcn_mfma_f32_16x16x32_bf16(av[i], bv[j], acc[i][j], 0, 0, 0);
    __builtin_amdgcn_s_setprio(0);
    if (kc + 1 < 16) { QSTAGE_WRITE(lds[cur ^ 1]); }
    __syncthreads();
    cur ^= 1;
  }
#undef QSTAGE_LOAD
#undef QSTAGE_WRITE

  const int M0w = M0 + wm * 64, N0w = N0 + wn * 64;
  if (z < 2) {
    ushort* out = (z == 0) ? qb : kb;
    float bn[4];
#pragma unroll
    for (int nt = 0; nt < 4; ++nt) bn[nt] = bias[N0w + nt * 16 + l15];
#pragma unroll
    for (int mt = 0; mt < 4; ++mt)
#pragma unroll
      for (int nt = 0; nt < 4; ++nt)
#pragma unroll
        for (int r = 0; r < 4; ++r) {
          const int m = M0w + mt * 16 + 4 * g + r;
          const int n = N0w + nt * 16 + l15;
          out[(size_t)m * 512 + n] = f2bf(acc[mt][nt][r] + bn[nt]);
        }
  } else {
#pragma unroll
    for (int mt = 0; mt < 4; ++mt)
#pragma unroll
      for (int r = 0; r < 4; ++r) {
        const int m = M0w + mt * 16 + 4 * g + r;  // hid index of V
        const float bm = bias[m];
#pragma unroll
        for (int nt = 0; nt < 4; ++nt) {
          const int tok = N0w + nt * 16 + l15;
          const size_t off = ((size_t)((tok >> 10) * 512 + m)) * 1024 + (tok & 1023);
          vT[off] = f2bf(acc[mt][nt][r] + bm);
        }
      }
  }
}

// LDS-staged output projection: out = ab*Wo^T + bo (f32). Tile 64(M)x128(N),
// BK=32, 4 waves (2x2 quadrants of 32x64). grid (128, 4) = 512 blocks.
__global__ __launch_bounds__(256, 3)
void out_lds(const ushort* __restrict__ A, const ushort* __restrict__ B,
             const float* __restrict__ bias, float* __restrict__ out) {
  __shared__ char lds[2][15360];  // A[64 x 80B] (5120) | B[128 x 80B] at +5120
  const int tid = threadIdx.x;
  const int w = tid >> 6, lane = tid & 63;
  const int l15 = lane & 15, g = lane >> 4;
  const int M0 = blockIdx.x * 64, N0 = blockIdx.y * 128;

  const int sr = tid >> 2, sc = tid & 3;
  const ushort* Ag = A + (size_t)(M0 + sr) * 512 + sc * 8;
  const ushort* Bg = B + (size_t)(N0 + sr) * 512 + sc * 8;
  const int wro = sr * 80 + sc * 16;
  uint4 sa0, sb0, sb1;

#define OSTAGE_LOAD(kc_)                                      \
  sa0 = *(const uint4*)(Ag + (kc_) * 32);                     \
  sb0 = *(const uint4*)(Bg + (kc_) * 32);                     \
  sb1 = *(const uint4*)(Bg + (size_t)64 * 512 + (kc_) * 32);
#define OSTAGE_WRITE(buf)                                     \
  *(uint4*)&(buf)[wro] = sa0;                                 \
  *(uint4*)&(buf)[5120 + wro] = sb0;                          \
  *(uint4*)&(buf)[5120 + wro + 64 * 80] = sb1;

  const int wm = w >> 1, wn = w & 1;
  const int aro = (wm * 32 + l15) * 80 + g * 16;         // + t*1280, t<2
  const int bro = 5120 + (wn * 64 + l15) * 80 + g * 16;  // + t*1280, t<4

  f32x4 acc[2][4];
#pragma unroll
  for (int i = 0; i < 2; ++i)
#pragma unroll
    for (int j = 0; j < 4; ++j) acc[i][j] = (f32x4){0.f, 0.f, 0.f, 0.f};

  OSTAGE_LOAD(0);
  OSTAGE_WRITE(lds[0]);
  __syncthreads();
  int cur = 0;
#pragma unroll 1
  for (int kc = 0; kc < 16; ++kc) {
    if (kc + 1 < 16) { OSTAGE_LOAD(kc + 1); }
    bf16x8 av[2], bv[4];
#pragma unroll
    for (int t = 0; t < 2; ++t) av[t] = *(const bf16x8*)&lds[cur][aro + t * 1280];
#pragma unroll
    for (int t = 0; t < 4; ++t) bv[t] = *(const bf16x8*)&lds[cur][bro + t * 1280];
    __builtin_amdgcn_s_setprio(1);
#pragma unroll
    for (int i = 0; i < 2; ++i)
#pragma unroll
      for (int j = 0; j < 4; ++j)
        acc[i][j] = __builtin_amdgcn_mfma_f32_16x16x32_bf16(av[i], bv[j], acc[i][j], 0, 0, 0);
    __builtin_amdgcn_s_setprio(0);
    if (kc + 1 < 16) { OSTAGE_WRITE(lds[cur ^ 1]); }
    __syncthreads();
    cur ^= 1;
  }
#undef OSTAGE_LOAD
#undef OSTAGE_WRITE

  const int M0w = M0 + wm * 32, N0w = N0 + wn * 64;
  float bn[4];
#pragma unroll
  for (int nt = 0; nt < 4; ++nt) bn[nt] = bias[N0w + nt * 16 + l15];
#pragma unroll
  for (int mt = 0; mt < 2; ++mt)
#pragma unroll
    for (int nt = 0; nt < 4; ++nt)
#pragma unroll
      for (int r = 0; r < 4; ++r) {
        const int m = M0w + mt * 16 + 4 * g + r;
        const int n = N0w + nt * 16 + l15;
        out[(size_t)m * 512 + n] = acc[mt][nt][r] + bn[nt];
      }
}

// Cooperative flash attention (round-9 validated, unchanged).
__global__ __launch_bounds__(256, 2)
void attn_mfma(const ushort* __restrict__ qb, const ushort* __restrict__ kb,
               const ushort* __restrict__ vT, const int* __restrict__ tbm,
               const float* __restrict__ temb, const int* __restrict__ lens,
               ushort* __restrict__ ab) {
  __shared__ char kv[2][16384];   // [buf][K 8KB | V 8KB], swizzled
  __shared__ char pbuf[4][2048];  // per-wave P tile
  const int tid = threadIdx.x;
  const int w = tid >> 6;
  const int lane = tid & 63;
  const int l15 = lane & 15, g = lane >> 4;
  const int b = blockIdx.x, h = blockIdx.y, p = blockIdx.z;
  const int len = lens[b];
  const int GB = 15 - p;
  const int qbaseA = p * 64 + 16 * w;
  const int qbaseB = GB * 64 + 16 * w;

  const float te_src = temb[(lane & 7) * N_HEADS + h] * 1.44269504f;

  const int r0 = tid >> 3, c0 = tid & 7;
  const size_t kgrow = (size_t)(b * L_SEQ) * HID_DIM + h * HEAD_DIM + c0 * 8;
  const size_t vgrow = (size_t)((b * 8 + h) * 64 + r0) * L_SEQ + c0 * 8;
  const int so0 = (tid * 16) ^ ((r0 & 7) << 4);
  const int so1 = so0 + 4096;
  uint4 skA, skB, svA, svB;

#define STAGE_LOAD(kc_)                                                      \
  skA = *(const uint4*)(kb + kgrow + (size_t)((kc_) + r0) * HID_DIM);        \
  skB = *(const uint4*)(kb + kgrow + (size_t)((kc_) + r0 + 32) * HID_DIM);   \
  svA = *(const uint4*)(vT + vgrow + (kc_));                                 \
  svB = *(const uint4*)(vT + vgrow + 32 * L_SEQ + (kc_));

#define STAGE_WRITE(dst)                                                     \
  *(uint4*)&(dst)[so0] = skA;                                                \
  *(uint4*)&(dst)[so1] = skB;                                                \
  *(uint4*)&(dst)[8192 + so0] = svA;                                         \
  *(uint4*)&(dst)[8192 + so1] = svB;

  bf16x8 qfA[2], qfB[2];
  {
    const ushort* qr = qb + (size_t)(b * L_SEQ + qbaseA + l15) * HID_DIM + h * HEAD_DIM + 8 * g;
    qfA[0] = *(const bf16x8*)(qr);
    qfA[1] = *(const bf16x8*)(qr + 32);
    qr = qb + (size_t)(b * L_SEQ + qbaseB + l15) * HID_DIM + h * HEAD_DIM + 8 * g;
    qfB[0] = *(const bf16x8*)(qr);
    qfB[1] = *(const bf16x8*)(qr + 32);
  }

  f32x4 OA[4], OB[4];
#pragma unroll
  for (int ct = 0; ct < 4; ++ct) {
    OA[ct] = (f32x4){0.f, 0.f, 0.f, 0.f};
    OB[ct] = (f32x4){0.f, 0.f, 0.f, 0.f};
  }
  float ssA[4] = {0.f, 0.f, 0.f, 0.f}, ssB[4] = {0.f, 0.f, 0.f, 0.f};
  bf16x8 kf[4][2], vf[2][4];
  int tbA_[4][4], tbB_[4][4];

  const int lenc = (len - 1) >> 6;
  const int nchB = (GB * 64 < len) ? ((GB < lenc ? GB : lenc) + 1) : 0;
  const int NCH = (p + 1 > nchB) ? (p + 1) : nchB;

#define LOAD_TB(dst, qbaseT, kc_)                                            \
  {                                                                          \
    const int* tb_p = tbm + (size_t)(b * L_SEQ + (qbaseT)) * L_SEQ + (kc_);  \
    _Pragma("unroll") for (int kt = 0; kt < 4; ++kt)                         \
      _Pragma("unroll") for (int r = 0; r < 4; ++r)                          \
        dst[kt][r] = tb_p[(4 * g + r) * L_SEQ + 16 * kt + l15];              \
  }

#define LOAD_KV_FRAGS(kvb)                                                   \
  _Pragma("unroll") for (int kt = 0; kt < 4; ++kt)                           \
    _Pragma("unroll") for (int db = 0; db < 2; ++db) {                       \
      const int off = ((2048 * kt + 128 * l15 + 16 * (g + 4 * db)) ^ ((l15 & 7) << 4)); \
      kf[kt][db] = *(const bf16x8*)&(kvb)[off];                              \
    }                                                                        \
  _Pragma("unroll") for (int kblk = 0; kblk < 2; ++kblk)                     \
    _Pragma("unroll") for (int ct = 0; ct < 4; ++ct) {                       \
      const int off = 8192 + ((2048 * ct + 128 * l15 + 16 * (4 * kblk + g)) ^ ((l15 & 7) << 4)); \
      vf[kblk][ct] = *(const bf16x8*)&(kvb)[off];                            \
    }

#define COMPUTE_TILE(qfv, Ov, ssumv, tbv, qbaseT, kc_)                       \
  {                                                                          \
    f32x4 s[4];                                                              \
    __builtin_amdgcn_s_setprio(1);                                           \
    _Pragma("unroll") for (int kt = 0; kt < 4; ++kt) {                       \
      s[kt] = (f32x4){0.f, 0.f, 0.f, 0.f};                                   \
      s[kt] = __builtin_amdgcn_mfma_f32_16x16x32_bf16(qfv[0], kf[kt][0], s[kt], 0, 0, 0); \
      s[kt] = __builtin_amdgcn_mfma_f32_16x16x32_bf16(qfv[1], kf[kt][1], s[kt], 0, 0, 0); \
    }                                                                        \
    __builtin_amdgcn_s_setprio(0);                                           \
    _Pragma("unroll") for (int kt = 0; kt < 4; ++kt) {                       \
      const int kg = (kc_) + 16 * kt + l15;                                  \
      _Pragma("unroll") for (int r = 0; r < 4; ++r) {                        \
        const int lr = 4 * g + r;                                            \
        const int qg = (qbaseT) + lr;                                        \
        const float te2 = __int_as_float(                                    \
            __builtin_amdgcn_ds_bpermute(tbv[kt][r] << 2, __float_as_int(te_src))); \
        float pp = exp2f(fmaf(s[kt][r], 0.18033688f, te2));                  \
        pp = (kg <= qg && qg < len) ? pp : 0.0f;                             \
        const ushort pbits = f2bf(pp);                                       \
        ssumv[r] += __bfloat162float(*(const __hip_bfloat16*)&pbits);        \
        const int off = ((lr * 128 + (16 * kt + l15) * 2) ^ ((lr & 7) << 4)); \
        *(ushort*)&pbuf[w][off] = pbits;                                     \
      }                                                                      \
    }                                                                        \
    _Pragma("unroll") for (int kblk = 0; kblk < 2; ++kblk) {                 \
      const int off = ((l15 * 128 + kblk * 64 + 16 * g) ^ ((l15 & 7) << 4)); \
      const bf16x8 pf = *(const bf16x8*)(&pbuf[w][off]);                     \
      __builtin_amdgcn_s_setprio(1);                                         \
      _Pragma("unroll") for (int ct = 0; ct < 4; ++ct)                       \
        Ov[ct] = __builtin_amdgcn_mfma_f32_16x16x32_bf16(pf, vf[kblk][ct], Ov[ct], 0, 0, 0); \
      __builtin_amdgcn_s_setprio(0);                                         \
    }                                                                        \
  }

  STAGE_LOAD(0);
  STAGE_WRITE(kv[0]);
  __syncthreads();

  int cur = 0;
  for (int c = 0; c < NCH; ++c) {
    const int kc = c * 64;
    const bool doB = (c < nchB);
    const bool doA = (c <= p);
    if (doB) LOAD_TB(tbB_, qbaseB, kc);
    if (doA) LOAD_TB(tbA_, qbaseA, kc);
    if (c + 1 < NCH) { STAGE_LOAD(kc + 64); }
    LOAD_KV_FRAGS(kv[cur]);
    if (doB) COMPUTE_TILE(qfB, OB, ssB, tbB_, qbaseB, kc);
    if (doA) COMPUTE_TILE(qfA, OA, ssA, tbA_, qbaseA, kc);
    if (c + 1 < NCH) { STAGE_WRITE(kv[cur ^ 1]); }
    __syncthreads();
    cur ^= 1;
  }

#define EPILOGUE(Ov, ssumv, qbaseT)                                          \
  {                                                                          \
    _Pragma("unroll") for (int m = 1; m <= 8; m <<= 1)                       \
      _Pragma("unroll") for (int r = 0; r < 4; ++r)                          \
        ssumv[r] += __shfl_xor(ssumv[r], m, 64);                             \
    _Pragma("unroll") for (int ct = 0; ct < 4; ++ct)                         \
      _Pragma("unroll") for (int r = 0; r < 4; ++r) {                        \
        const int qg = (qbaseT) + 4 * g + r;                                 \
        const float inv = (qg < len) ? 1.0f / ssumv[r] : 0.0f;               \
        ab[(size_t)(b * L_SEQ + qg) * HID_DIM + h * HEAD_DIM + 16 * ct + l15] = \
            f2bf(Ov[ct][r] * inv);                                           \
      }                                                                      \
  }

  EPILOGUE(OA, ssA, qbaseA);
  EPILOGUE(OB, ssB, qbaseB);
}

extern "C" void kernel_launch(void* const* d_in, const int* in_sizes, int n_in,
                              void* d_out, int out_size, void* d_ws, size_t ws_size,
                              hipStream_t stream) {
  const float* x    = (const float*)d_in[0];
  const int*   tbm  = (const int*)d_in[1];
  // d_in[2] = causal_mask: deterministic triu(k=1) -> handled analytically
  const uint8_t* pm = (const uint8_t*)d_in[3];
  const float* Wq = (const float*)d_in[4];
  const float* bq = (const float*)d_in[5];
  const float* Wk = (const float*)d_in[6];
  const float* bk = (const float*)d_in[7];
  const float* Wv = (const float*)d_in[8];
  const float* bv = (const float*)d_in[9];
  const float* Wo = (const float*)d_in[10];
  const float* bo = (const float*)d_in[11];
  const float* temb = (const float*)d_in[12];
  float* out = (float*)d_out;

  const size_t NTOK = (size_t)BATCH * L_SEQ * HID_DIM;  // 4,194,304
  const size_t NW = 262144;
  ushort* ab  = (ushort*)d_ws;        // bf16 attention output [8192][512]
  ushort* xb  = ab + NTOK;            // bf16 x
  ushort* wqb = xb + NTOK;
  ushort* wkb = wqb + NW;
  ushort* wvb = wkb + NW;
  ushort* wob = wvb + NW;
  ushort* qb  = wob + NW;             // bf16 Q [tok][512]
  ushort* kb  = qb + NTOK;            // bf16 K [tok][512]
  ushort* vT  = kb + NTOK;            // bf16 V^T [b*8+h][64][1024]
  int* lens   = (int*)(vT + NTOK);

  prep_convert<<<2560, 256, 0, stream>>>(x, Wq, Wk, Wv, Wo, xb);
  lens_kernel<<<8, 256, 0, stream>>>(pm, lens);
  qkv_lds<<<dim3(64, 4, 3), 256, 0, stream>>>(xb, wqb, wkb, wvb, bq, bk, bv, qb, kb, vT);
  attn_mfma<<<dim3(8, 8, 8), 256, 0, stream>>>(qb, kb, vT, tbm, temb, lens, ab);
  out_lds<<<dim3(128, 4), 256, 0, stream>>>(ab, wob, bo, out);
}